// Round 2
// baseline (463.064 us; speedup 1.0000x reference)
//
#include <hip/hip_runtime.h>

// ---------------------------------------------------------------------------
// SpatialTransformer attention, dtype-robust (detects fp32 vs bf16 storage).
// Pipeline (all bf16 compute, fp32 MFMA accum):
//   detect storage -> convert inputs to bf16 ws copies
//   Q = x@Wq^T+bq ; K = ce@Wk^T+bk ; V = ce@Wv^T+bv
//   S = QK^T/32 (bf16) ; softmax rows in place -> P
//   Vt = V^T ; A = x + P@Vt^T ; out = A@Wo^T + bo ; writer emits storage fmt
// GEMM: 128x128 tile, 4 waves (2x2) of 64x64, mfma_f32_16x16x32_bf16,
// global_load_lds width=16 (m97 structure).
// ---------------------------------------------------------------------------

typedef __attribute__((ext_vector_type(8))) short short8;
typedef __attribute__((ext_vector_type(4))) float f32x4;

__device__ __forceinline__ float b2f(unsigned short u) {
  union { unsigned int i; float f; } x;
  x.i = ((unsigned int)u) << 16;
  return x.f;
}
__device__ __forceinline__ unsigned short f2b(float f) {
  union { float f; unsigned int i; } x;
  x.f = f;
  unsigned int i = x.i;
  i += 0x7fffu + ((i >> 16) & 1u);  // RNE
  return (unsigned short)(i >> 16);
}

__device__ __forceinline__ void async_copy16(const void* g, void* l) {
  __builtin_amdgcn_global_load_lds(
      (const __attribute__((address_space(1))) unsigned int*)g,
      (__attribute__((address_space(3))) unsigned int*)l, 16, 0, 0);
}

// --- storage-format detector: fp32 storage => even ushorts are mantissa bits
__global__ void detect_fmt(const unsigned short* __restrict__ x, int* flag) {
  __shared__ int cnt;
  if (threadIdx.x == 0) cnt = 0;
  __syncthreads();
  int c = 0;
  for (int i = threadIdx.x * 2; i < 8192; i += 512) {  // even indices
    unsigned e = (x[i] >> 7) & 0xFF;
    if (e >= 0x90) ++c;  // |v| >= 2^17 impossible for sane bf16 data
  }
  atomicAdd(&cnt, c);
  __syncthreads();
  if (threadIdx.x == 0) *flag = (cnt > 64) ? 1 : 0;
}

// --- normalize an input tensor into a bf16 ws copy
__global__ __launch_bounds__(256) void convert_in(
    const void* __restrict__ src, unsigned short* __restrict__ dst,
    const int* __restrict__ flag, long n) {
  const bool f32 = (*flag != 0);
  const long stride = (long)gridDim.x * blockDim.x;
  for (long i = blockIdx.x * 256L + threadIdx.x; i < n; i += stride) {
    dst[i] = f32 ? f2b(((const float*)src)[i]) : ((const unsigned short*)src)[i];
  }
}

// --- emit output in the detected storage format
__global__ __launch_bounds__(256) void write_out(
    const unsigned short* __restrict__ O, void* __restrict__ out,
    const int* __restrict__ flag, long n) {
  const bool f32 = (*flag != 0);
  const long stride = (long)gridDim.x * blockDim.x;
  for (long i = blockIdx.x * 256L + threadIdx.x; i < n; i += stride) {
    if (f32) ((float*)out)[i] = b2f(O[i]);
    else     ((unsigned short*)out)[i] = O[i];
  }
}

#define MODE_BIAS 0  // bf16 out = acc + bias[n]
#define MODE_RES  2  // bf16 out = acc + res[m,n]
#define MODE_SB   3  // bf16 out = acc * scale

// C[m,n] = sum_k A[m,k]*B[n,k]  (row-major NT). grid=(N/128, M/128, batch)
template <int MODE>
__global__ __launch_bounds__(256, 2) void gemm_nt(
    const unsigned short* __restrict__ A, const unsigned short* __restrict__ B,
    unsigned short* __restrict__ C, const unsigned short* __restrict__ bias,
    const unsigned short* __restrict__ Res, int M, int N, int K, float scale,
    long sA, long sB, long sC, long sR) {
  __shared__ __align__(16) unsigned short As[128 * 32];
  __shared__ __align__(16) unsigned short Bs[128 * 32];
  const int bz = blockIdx.z;
  const unsigned short* Ab = A + bz * sA;
  const unsigned short* Bb = B + bz * sB;
  const int tid = threadIdx.x;
  const int wave = tid >> 6, lane = tid & 63;
  const int wm = wave >> 1, wn = wave & 1;
  const int quad = lane >> 4, lrow = lane & 15;

  const long arow0 = (long)blockIdx.y * 128 + (tid >> 2);
  const long brow0 = (long)blockIdx.x * 128 + (tid >> 2);
  const int cstg = (tid & 3) * 8;
  const unsigned short* ag0 = Ab + arow0 * K + cstg;
  const unsigned short* ag1 = ag0 + 64L * K;
  const unsigned short* bg0 = Bb + brow0 * K + cstg;
  const unsigned short* bg1 = bg0 + 64L * K;
  char* lA0 = (char*)As + tid * 16;
  char* lA1 = (char*)As + (256 + tid) * 16;
  char* lB0 = (char*)Bs + tid * 16;
  char* lB1 = (char*)Bs + (256 + tid) * 16;

  f32x4 acc[4][4];
#pragma unroll
  for (int i = 0; i < 4; ++i)
#pragma unroll
    for (int j = 0; j < 4; ++j) acc[i][j] = (f32x4){0.f, 0.f, 0.f, 0.f};

  for (int kt = 0; kt < K; kt += 32) {
    async_copy16(ag0 + kt, lA0);
    async_copy16(ag1 + kt, lA1);
    async_copy16(bg0 + kt, lB0);
    async_copy16(bg1 + kt, lB1);
    __syncthreads();

    short8 af[4], bfr[4];
#pragma unroll
    for (int i = 0; i < 4; ++i)
      af[i] = *(const short8*)(As + (wm * 64 + i * 16 + lrow) * 32 + quad * 8);
#pragma unroll
    for (int j = 0; j < 4; ++j)
      bfr[j] = *(const short8*)(Bs + (wn * 64 + j * 16 + lrow) * 32 + quad * 8);
#pragma unroll
    for (int i = 0; i < 4; ++i)
#pragma unroll
      for (int j = 0; j < 4; ++j)
        acc[i][j] = __builtin_amdgcn_mfma_f32_16x16x32_bf16(af[i], bfr[j],
                                                            acc[i][j], 0, 0, 0);
    __syncthreads();
  }

  // C/D layout: col=lane&15, row=(lane>>4)*4+reg  (m89-verified)
#pragma unroll
  for (int i = 0; i < 4; ++i) {
    const long row = (long)blockIdx.y * 128 + wm * 64 + i * 16 + quad * 4;
#pragma unroll
    for (int j = 0; j < 4; ++j) {
      const long col = (long)blockIdx.x * 128 + wn * 64 + j * 16 + lrow;
#pragma unroll
      for (int r = 0; r < 4; ++r) {
        const float v = acc[i][j][r];
        const long idx = (row + r) * N + col;
        if (MODE == MODE_BIAS) {
          C[bz * sC + idx] = f2b(v + b2f(bias[col]));
        } else if (MODE == MODE_SB) {
          C[bz * sC + idx] = f2b(v * scale);
        } else {
          C[bz * sC + idx] = f2b(v + b2f(Res[bz * sR + idx]));
        }
      }
    }
  }
}

// out[b][c][r] = in[b][r][c]; grid (cols/32, rows/32, batch)
__global__ __launch_bounds__(256) void transpose2d(
    const unsigned short* __restrict__ in, unsigned short* __restrict__ out,
    int rows, int cols) {
  __shared__ unsigned short tile[32][33];
  const long b = blockIdx.z;
  in += b * (long)rows * cols;
  out += b * (long)rows * cols;
  const int r0 = blockIdx.y * 32, c0 = blockIdx.x * 32;
  const int tx = threadIdx.x & 31, ty = threadIdx.x >> 5;
#pragma unroll
  for (int i = 0; i < 32; i += 8)
    tile[ty + i][tx] = in[(long)(r0 + ty + i) * cols + (c0 + tx)];
  __syncthreads();
#pragma unroll
  for (int i = 0; i < 32; i += 8)
    out[(long)(c0 + ty + i) * rows + (r0 + tx)] = tile[tx][ty + i];
}

// in-place row softmax over 2048 bf16 scores; one block per row
__global__ __launch_bounds__(256) void softmax_rows(
    unsigned short* __restrict__ SP) {
  unsigned short* s = SP + blockIdx.x * 2048L;
  const int tid = threadIdx.x;
  float v[8];
#pragma unroll
  for (int i = 0; i < 8; ++i) v[i] = b2f(s[tid + 256 * i]);
  float m = v[0];
#pragma unroll
  for (int i = 1; i < 8; ++i) m = fmaxf(m, v[i]);
#pragma unroll
  for (int off = 32; off > 0; off >>= 1) m = fmaxf(m, __shfl_xor(m, off));
  __shared__ float redm[4], reds[4];
  if ((tid & 63) == 0) redm[tid >> 6] = m;
  __syncthreads();
  m = fmaxf(fmaxf(redm[0], redm[1]), fmaxf(redm[2], redm[3]));
  float sum = 0.f;
#pragma unroll
  for (int i = 0; i < 8; ++i) {
    v[i] = __expf(v[i] - m);
    sum += v[i];
  }
#pragma unroll
  for (int off = 32; off > 0; off >>= 1) sum += __shfl_xor(sum, off);
  if ((tid & 63) == 0) reds[tid >> 6] = sum;
  __syncthreads();
  sum = reds[0] + reds[1] + reds[2] + reds[3];
  const float inv = 1.0f / sum;
#pragma unroll
  for (int i = 0; i < 8; ++i) s[tid + 256 * i] = f2b(v[i] * inv);
}

extern "C" void kernel_launch(void* const* d_in, const int* in_sizes, int n_in,
                              void* d_out, int out_size, void* d_ws,
                              size_t ws_size, hipStream_t stream) {
  char* ws = (char*)d_ws;
  const long MB = 1 << 20;
  // layout (MiB): high-water 121
  unsigned short* xb  = (unsigned short*)(ws + 0 * MB);    // 0-16
  unsigned short* Wob = (unsigned short*)(ws + 16 * MB);   // 16-18
  unsigned short* bqb = (unsigned short*)(ws + 18 * MB);
  unsigned short* bkb = (unsigned short*)(ws + 18 * MB + 8192);
  unsigned short* bvb = (unsigned short*)(ws + 18 * MB + 16384);
  unsigned short* bob = (unsigned short*)(ws + 18 * MB + 24576);
  int*            flg = (int*)           (ws + 18 * MB + 65536);
  unsigned short* ceb = (unsigned short*)(ws + 19 * MB);   // 19-35
  unsigned short* Wqb = (unsigned short*)(ws + 35 * MB);   // 35-37
  unsigned short* Wkb = (unsigned short*)(ws + 37 * MB);   // 37-39
  unsigned short* Wvb = (unsigned short*)(ws + 39 * MB);   // 39-41
  unsigned short* Q   = (unsigned short*)(ws + 41 * MB);   // 41-57
  unsigned short* Kp  = (unsigned short*)(ws + 57 * MB);   // 57-73
  unsigned short* Vp  = (unsigned short*)(ws + 73 * MB);   // 73-89
  unsigned short* S   = (unsigned short*)(ws + 89 * MB);   // 89-121 (->P)
  unsigned short* Vt  = (unsigned short*)(ws + 41 * MB);   // reuse Q
  unsigned short* Ar  = (unsigned short*)(ws + 57 * MB);   // reuse K
  unsigned short* O   = (unsigned short*)(ws + 19 * MB);   // reuse ce

  const dim3 blk(256);
  const float scale = 0.03125f;  // 1/sqrt(1024)
  const long nBSC = 4L * 2048 * 1024;

  detect_fmt<<<dim3(1), blk, 0, stream>>>((const unsigned short*)d_in[0], flg);

  convert_in<<<dim3(1024), blk, 0, stream>>>(d_in[0], xb,  flg, nBSC);
  convert_in<<<dim3(1024), blk, 0, stream>>>(d_in[1], ceb, flg, nBSC);
  convert_in<<<dim3(256),  blk, 0, stream>>>(d_in[2], Wqb, flg, 1024L * 1024);
  convert_in<<<dim3(4),    blk, 0, stream>>>(d_in[3], bqb, flg, 1024);
  convert_in<<<dim3(256),  blk, 0, stream>>>(d_in[4], Wkb, flg, 1024L * 1024);
  convert_in<<<dim3(4),    blk, 0, stream>>>(d_in[5], bkb, flg, 1024);
  convert_in<<<dim3(256),  blk, 0, stream>>>(d_in[6], Wvb, flg, 1024L * 1024);
  convert_in<<<dim3(4),    blk, 0, stream>>>(d_in[7], bvb, flg, 1024);
  convert_in<<<dim3(256),  blk, 0, stream>>>(d_in[8], Wob, flg, 1024L * 1024);
  convert_in<<<dim3(4),    blk, 0, stream>>>(d_in[9], bob, flg, 1024);

  // QKV projections: M=8192 (batch folded), N=K=1024
  gemm_nt<MODE_BIAS><<<dim3(8, 64, 1), blk, 0, stream>>>(
      xb, Wqb, Q, bqb, nullptr, 8192, 1024, 1024, 1.f, 0, 0, 0, 0);
  gemm_nt<MODE_BIAS><<<dim3(8, 64, 1), blk, 0, stream>>>(
      ceb, Wkb, Kp, bkb, nullptr, 8192, 1024, 1024, 1.f, 0, 0, 0, 0);
  gemm_nt<MODE_BIAS><<<dim3(8, 64, 1), blk, 0, stream>>>(
      ceb, Wvb, Vp, bvb, nullptr, 8192, 1024, 1024, 1.f, 0, 0, 0, 0);

  // S = QK^T * scale (bf16), per batch 2048x2048, K=1024
  gemm_nt<MODE_SB><<<dim3(16, 16, 4), blk, 0, stream>>>(
      Q, Kp, S, nullptr, nullptr, 2048, 2048, 1024, scale,
      2048L * 1024, 2048L * 1024, 2048L * 2048, 0);

  // Vt = V^T per batch (into dead Q slot)
  transpose2d<<<dim3(32, 64, 4), blk, 0, stream>>>(Vp, Vt, 2048, 1024);

  // P = softmax(S) in place
  softmax_rows<<<dim3(8192), blk, 0, stream>>>(S);

  // A = x + P@V : per batch M=2048, N=1024, K=2048 (B=Vt, NT)
  gemm_nt<MODE_RES><<<dim3(8, 16, 4), blk, 0, stream>>>(
      S, Vt, Ar, nullptr, xb, 2048, 1024, 2048, 1.f,
      2048L * 2048, 1024L * 2048, 2048L * 1024, 2048L * 1024);

  // out = A@Wo^T + bo : M=8192, N=K=1024
  gemm_nt<MODE_BIAS><<<dim3(8, 64, 1), blk, 0, stream>>>(
      Ar, Wob, O, bob, nullptr, 8192, 1024, 1024, 1.f, 0, 0, 0, 0);

  write_out<<<dim3(1024), blk, 0, stream>>>(O, d_out, flg, nBSC);
}

// Round 3
// 389.144 us; speedup vs baseline: 1.1900x; 1.1900x over previous
//
#include <hip/hip_runtime.h>

// ---------------------------------------------------------------------------
// SpatialTransformer attention, dtype-robust (fp32 vs bf16 storage detect).
// Round 3: occupancy-directed. QKV merged into one z=3 dispatch (1536 blocks),
// PV and out-proj use 64x128 tiles (1024 blocks = 4 blocks/CU), all input
// conversions fused into ONE kernel writing a contiguous bf16 concat region.
// GEMM core: m97 structure (BMx128 tile, BK=32, mfma_f32_16x16x32_bf16,
// global_load_lds width=16, fp32 accum).
// ---------------------------------------------------------------------------

typedef __attribute__((ext_vector_type(8))) short short8;
typedef __attribute__((ext_vector_type(8))) unsigned short ushort8;
typedef __attribute__((ext_vector_type(4))) float f32x4;

__device__ __forceinline__ float b2f(unsigned short u) {
  union { unsigned int i; float f; } x;
  x.i = ((unsigned int)u) << 16;
  return x.f;
}
__device__ __forceinline__ unsigned short f2b(float f) {
  union { float f; unsigned int i; } x;
  x.f = f;
  unsigned int i = x.i;
  i += 0x7fffu + ((i >> 16) & 1u);  // RNE
  return (unsigned short)(i >> 16);
}

__device__ __forceinline__ void async_copy16(const void* g, void* l) {
  __builtin_amdgcn_global_load_lds(
      (const __attribute__((address_space(1))) unsigned int*)g,
      (__attribute__((address_space(3))) unsigned int*)l, 16, 0, 0);
}

// --- storage-format detector: fp32 storage => even ushorts are mantissa bits
__global__ void detect_fmt(const unsigned short* __restrict__ x, int* flag) {
  __shared__ int cnt;
  if (threadIdx.x == 0) cnt = 0;
  __syncthreads();
  int c = 0;
  for (int i = threadIdx.x * 2; i < 8192; i += 512) {
    unsigned e = (x[i] >> 7) & 0xFF;
    if (e >= 0x90) ++c;
  }
  atomicAdd(&cnt, c);
  __syncthreads();
  if (threadIdx.x == 0) *flag = (cnt > 64) ? 1 : 0;
}

// --- one fused conversion of all 10 inputs into a contiguous bf16 concat
// elem offsets (8-elem chunks guaranteed aligned):
//  x 0 | ce 8388608 | Wq 16777216 | bq 17825792 | Wk 17826816 | bk 18875392
//  Wv 18876416 | bv 19924992 | Wo 19926016 | bo 20974592 | total 20975616
struct CvtArgs { const void* src[10]; };

__global__ __launch_bounds__(256) void convert_all(
    CvtArgs a, unsigned short* __restrict__ dst, const int* __restrict__ flag) {
  const bool f32 = (*flag != 0);
  const long nchunk = 2621952;  // 20975616 / 8
  for (long c = blockIdx.x * 256L + threadIdx.x; c < nchunk;
       c += 1024L * 256) {
    const long flat = c * 8;
    int t; long off;
    if      (flat < 8388608)  { t = 0; off = 0; }
    else if (flat < 16777216) { t = 1; off = 8388608; }
    else if (flat < 17825792) { t = 2; off = 16777216; }
    else if (flat < 17826816) { t = 3; off = 17825792; }
    else if (flat < 18875392) { t = 4; off = 17826816; }
    else if (flat < 18876416) { t = 5; off = 18875392; }
    else if (flat < 19924992) { t = 6; off = 18876416; }
    else if (flat < 19926016) { t = 7; off = 19924992; }
    else if (flat < 20974592) { t = 8; off = 19926016; }
    else                      { t = 9; off = 20974592; }
    const long li = flat - off;
    if (f32) {
      const float* s = (const float*)a.src[t] + li;
      const f32x4 lo = *(const f32x4*)s;
      const f32x4 hi = *(const f32x4*)(s + 4);
      ushort8 o;
      o[0] = f2b(lo[0]); o[1] = f2b(lo[1]); o[2] = f2b(lo[2]); o[3] = f2b(lo[3]);
      o[4] = f2b(hi[0]); o[5] = f2b(hi[1]); o[6] = f2b(hi[2]); o[7] = f2b(hi[3]);
      *(ushort8*)(dst + flat) = o;
    } else {
      *(ushort8*)(dst + flat) =
          *(const ushort8*)((const unsigned short*)a.src[t] + li);
    }
  }
}

// --- emit output in the detected storage format (x8 vectorized)
__global__ __launch_bounds__(256) void write_out(
    const unsigned short* __restrict__ O, void* __restrict__ out,
    const int* __restrict__ flag) {
  const bool f32 = (*flag != 0);
  const long nchunk = 1048576;  // 8388608 / 8
  for (long c = blockIdx.x * 256L + threadIdx.x; c < nchunk;
       c += 1024L * 256) {
    const long flat = c * 8;
    const ushort8 v = *(const ushort8*)(O + flat);
    if (f32) {
      f32x4 lo, hi;
      lo[0] = b2f(v[0]); lo[1] = b2f(v[1]); lo[2] = b2f(v[2]); lo[3] = b2f(v[3]);
      hi[0] = b2f(v[4]); hi[1] = b2f(v[5]); hi[2] = b2f(v[6]); hi[3] = b2f(v[7]);
      *(f32x4*)((float*)out + flat) = lo;
      *(f32x4*)((float*)out + flat + 4) = hi;
    } else {
      *(ushort8*)((unsigned short*)out + flat) = v;
    }
  }
}

#define MODE_BIAS 0  // bf16 out = acc + bias[n]
#define MODE_RES  2  // bf16 out = acc + res[m,n]
#define MODE_SB   3  // bf16 out = acc * scale

// Core NT GEMM tile: C[m,n] += sum_k A[m,k]*B[n,k], BM x 128 block tile,
// BK=32, 4 waves. BM=128: wave-tile 64x64 (acc 4x4); BM=64: 32x64 (acc 2x4).
template <int MODE, int BM>
__device__ __forceinline__ void gemm_core(
    const unsigned short* __restrict__ A, const unsigned short* __restrict__ B,
    unsigned short* __restrict__ C, const unsigned short* __restrict__ bias,
    const unsigned short* __restrict__ Res, int N, int K, float scale,
    int bx, int by) {
  constexpr int MI = BM / 32;  // acc row-frags per wave
  __shared__ __align__(16) unsigned short As[BM * 32];
  __shared__ __align__(16) unsigned short Bs[128 * 32];
  const int tid = threadIdx.x;
  const int wave = tid >> 6, lane = tid & 63;
  const int wm = wave >> 1, wn = wave & 1;
  const int quad = lane >> 4, lrow = lane & 15;

  const long arow0 = (long)by * BM + (tid >> 2);
  const long brow0 = (long)bx * 128 + (tid >> 2);
  const int cstg = (tid & 3) * 8;
  const unsigned short* ag0 = A + arow0 * K + cstg;
  const unsigned short* ag1 = ag0 + 64L * K;  // BM=128 only
  const unsigned short* bg0 = B + brow0 * K + cstg;
  const unsigned short* bg1 = bg0 + 64L * K;
  char* lA0 = (char*)As + tid * 16;
  char* lA1 = (char*)As + (256 + tid) * 16;
  char* lB0 = (char*)Bs + tid * 16;
  char* lB1 = (char*)Bs + (256 + tid) * 16;

  f32x4 acc[MI][4];
#pragma unroll
  for (int i = 0; i < MI; ++i)
#pragma unroll
    for (int j = 0; j < 4; ++j) acc[i][j] = (f32x4){0.f, 0.f, 0.f, 0.f};

  for (int kt = 0; kt < K; kt += 32) {
    async_copy16(ag0 + kt, lA0);
    if (BM == 128) async_copy16(ag1 + kt, lA1);
    async_copy16(bg0 + kt, lB0);
    async_copy16(bg1 + kt, lB1);
    __syncthreads();

    short8 af[MI], bfr[4];
#pragma unroll
    for (int i = 0; i < MI; ++i)
      af[i] = *(const short8*)(As + (wm * (BM / 2) + i * 16 + lrow) * 32 +
                               quad * 8);
#pragma unroll
    for (int j = 0; j < 4; ++j)
      bfr[j] = *(const short8*)(Bs + (wn * 64 + j * 16 + lrow) * 32 + quad * 8);
#pragma unroll
    for (int i = 0; i < MI; ++i)
#pragma unroll
      for (int j = 0; j < 4; ++j)
        acc[i][j] = __builtin_amdgcn_mfma_f32_16x16x32_bf16(af[i], bfr[j],
                                                            acc[i][j], 0, 0, 0);
    __syncthreads();
  }

  // C/D layout: col=lane&15, row=(lane>>4)*4+reg (m89-verified)
#pragma unroll
  for (int i = 0; i < MI; ++i) {
    const long row = (long)by * BM + wm * (BM / 2) + i * 16 + quad * 4;
#pragma unroll
    for (int j = 0; j < 4; ++j) {
      const long col = (long)bx * 128 + wn * 64 + j * 16 + lrow;
#pragma unroll
      for (int r = 0; r < 4; ++r) {
        const float v = acc[i][j][r];
        const long idx = (row + r) * N + col;
        if (MODE == MODE_BIAS) {
          C[idx] = f2b(v + b2f(bias[col]));
        } else if (MODE == MODE_SB) {
          C[idx] = f2b(v * scale);
        } else {
          C[idx] = f2b(v + b2f(Res[idx]));
        }
      }
    }
  }
}

template <int MODE, int BM>
__global__ __launch_bounds__(256, 2) void gemm_nt(
    const unsigned short* __restrict__ A, const unsigned short* __restrict__ B,
    unsigned short* __restrict__ C, const unsigned short* __restrict__ bias,
    const unsigned short* __restrict__ Res, int N, int K, float scale,
    long sA, long sB, long sC, long sR) {
  const int bz = blockIdx.z;
  const unsigned short* Rb = (MODE == MODE_RES) ? Res + bz * sR : nullptr;
  gemm_core<MODE, BM>(A + bz * sA, B + bz * sB, C + bz * sC, bias, Rb, N, K,
                      scale, blockIdx.x, blockIdx.y);
}

// merged Q/K/V projections: blockIdx.z selects (A,B,C,bias) triple
struct QkvArgs {
  const unsigned short* A[3];
  const unsigned short* B[3];
  unsigned short* C[3];
  const unsigned short* bias[3];
};
__global__ __launch_bounds__(256, 2) void gemm_qkv(QkvArgs a, int N, int K) {
  const int z = blockIdx.z;
  gemm_core<MODE_BIAS, 128>(a.A[z], a.B[z], a.C[z], a.bias[z], nullptr, N, K,
                            1.f, blockIdx.x, blockIdx.y);
}

// out[b][c][r] = in[b][r][c]; grid (cols/32, rows/32, batch)
__global__ __launch_bounds__(256) void transpose2d(
    const unsigned short* __restrict__ in, unsigned short* __restrict__ out,
    int rows, int cols) {
  __shared__ unsigned short tile[32][33];
  const long b = blockIdx.z;
  in += b * (long)rows * cols;
  out += b * (long)rows * cols;
  const int r0 = blockIdx.y * 32, c0 = blockIdx.x * 32;
  const int tx = threadIdx.x & 31, ty = threadIdx.x >> 5;
#pragma unroll
  for (int i = 0; i < 32; i += 8)
    tile[ty + i][tx] = in[(long)(r0 + ty + i) * cols + (c0 + tx)];
  __syncthreads();
#pragma unroll
  for (int i = 0; i < 32; i += 8)
    out[(long)(c0 + ty + i) * rows + (r0 + tx)] = tile[tx][ty + i];
}

// in-place row softmax over 2048 bf16 scores; one block per row
__global__ __launch_bounds__(256) void softmax_rows(
    unsigned short* __restrict__ SP) {
  unsigned short* s = SP + blockIdx.x * 2048L;
  const int tid = threadIdx.x;
  float v[8];
#pragma unroll
  for (int i = 0; i < 8; ++i) v[i] = b2f(s[tid + 256 * i]);
  float m = v[0];
#pragma unroll
  for (int i = 1; i < 8; ++i) m = fmaxf(m, v[i]);
#pragma unroll
  for (int off = 32; off > 0; off >>= 1) m = fmaxf(m, __shfl_xor(m, off));
  __shared__ float redm[4], reds[4];
  if ((tid & 63) == 0) redm[tid >> 6] = m;
  __syncthreads();
  m = fmaxf(fmaxf(redm[0], redm[1]), fmaxf(redm[2], redm[3]));
  float sum = 0.f;
#pragma unroll
  for (int i = 0; i < 8; ++i) {
    v[i] = __expf(v[i] - m);
    sum += v[i];
  }
#pragma unroll
  for (int off = 32; off > 0; off >>= 1) sum += __shfl_xor(sum, off);
  if ((tid & 63) == 0) reds[tid >> 6] = sum;
  __syncthreads();
  sum = reds[0] + reds[1] + reds[2] + reds[3];
  const float inv = 1.0f / sum;
#pragma unroll
  for (int i = 0; i < 8; ++i) s[tid + 256 * i] = f2b(v[i] * inv);
}

extern "C" void kernel_launch(void* const* d_in, const int* in_sizes, int n_in,
                              void* d_out, int out_size, void* d_ws,
                              size_t ws_size, hipStream_t stream) {
  char* ws = (char*)d_ws;
  const long MB = 1 << 20;
  // bf16 concat of all converted inputs at ws+0 (40.01 MiB)
  unsigned short* C0  = (unsigned short*)ws;
  unsigned short* xb  = C0;
  unsigned short* ceb = C0 + 8388608;
  unsigned short* Wqb = C0 + 16777216;
  unsigned short* bqb = C0 + 17825792;
  unsigned short* Wkb = C0 + 17826816;
  unsigned short* bkb = C0 + 18875392;
  unsigned short* Wvb = C0 + 18876416;
  unsigned short* bvb = C0 + 19924992;
  unsigned short* Wob = C0 + 19926016;
  unsigned short* bob = C0 + 20974592;
  int*            flg = (int*)(ws + 41 * MB);
  unsigned short* Q   = (unsigned short*)(ws + 42 * MB);  // 42-58
  unsigned short* Kp  = (unsigned short*)(ws + 58 * MB);  // 58-74
  unsigned short* Vp  = (unsigned short*)(ws + 74 * MB);  // 74-90
  unsigned short* S   = (unsigned short*)(ws + 90 * MB);  // 90-122 (->P)
  unsigned short* Vt  = Q;    // reuse Q slot after QK^T
  unsigned short* Ar  = Kp;   // reuse K slot after QK^T
  unsigned short* O   = Vp;   // reuse V slot after transpose

  const dim3 blk(256);
  const float scale = 0.03125f;  // 1/sqrt(1024)

  detect_fmt<<<dim3(1), dim3(256), 0, stream>>>((const unsigned short*)d_in[0],
                                                flg);
  CvtArgs ca;
  for (int i = 0; i < 10; ++i) ca.src[i] = d_in[i];
  convert_all<<<dim3(1024), blk, 0, stream>>>(ca, C0, flg);

  // merged QKV projections: M=8192 (batch folded), N=K=1024, 1536 blocks
  QkvArgs qa;
  qa.A[0] = xb;  qa.A[1] = ceb; qa.A[2] = ceb;
  qa.B[0] = Wqb; qa.B[1] = Wkb; qa.B[2] = Wvb;
  qa.C[0] = Q;   qa.C[1] = Kp;  qa.C[2] = Vp;
  qa.bias[0] = bqb; qa.bias[1] = bkb; qa.bias[2] = bvb;
  gemm_qkv<<<dim3(8, 64, 3), blk, 0, stream>>>(qa, 1024, 1024);

  // S = QK^T * scale (bf16), per batch 2048x2048, K=1024, 1024 blocks
  gemm_nt<MODE_SB, 128><<<dim3(16, 16, 4), blk, 0, stream>>>(
      Q, Kp, S, nullptr, nullptr, 2048, 1024, scale,
      2048L * 1024, 2048L * 1024, 2048L * 2048, 0);

  // Vt = V^T per batch (into dead Q slot)
  transpose2d<<<dim3(32, 64, 4), blk, 0, stream>>>(Vp, Vt, 2048, 1024);

  // P = softmax(S) in place
  softmax_rows<<<dim3(8192), blk, 0, stream>>>(S);

  // A = x + P@V : per batch M=2048, N=1024, K=2048; 64x128 tiles, 1024 blocks
  gemm_nt<MODE_RES, 64><<<dim3(8, 32, 4), blk, 0, stream>>>(
      S, Vt, Ar, nullptr, xb, 1024, 2048, 1.f,
      2048L * 2048, 1024L * 2048, 2048L * 1024, 2048L * 1024);

  // out = A@Wo^T + bo : M=8192, N=K=1024; 64x128 tiles, 1024 blocks
  gemm_nt<MODE_BIAS, 64><<<dim3(8, 128, 1), blk, 0, stream>>>(
      Ar, Wob, O, bob, nullptr, 1024, 1024, 1.f, 0, 0, 0, 0);

  write_out<<<dim3(1024), blk, 0, stream>>>(O, d_out, flg);
}

// Round 4
// 331.559 us; speedup vs baseline: 1.3966x; 1.1737x over previous
//
#include <hip/hip_runtime.h>

// ---------------------------------------------------------------------------
// SpatialTransformer attention, dtype-robust (fp32 vs bf16 storage detect).
// Round 4: all GEMMs at 128x128 tiles; KU=2 k-unroll (two BK=32 sub-tiles,
// one barrier per 64-K, 32KB LDS); XCD-band blockIdx swizzle for A-tile L2
// locality; out-proj epilogue writes d_out directly in detected format.
// ---------------------------------------------------------------------------

typedef __attribute__((ext_vector_type(8))) short short8;
typedef __attribute__((ext_vector_type(8))) unsigned short ushort8;
typedef __attribute__((ext_vector_type(4))) float f32x4;

__device__ __forceinline__ float b2f(unsigned short u) {
  union { unsigned int i; float f; } x;
  x.i = ((unsigned int)u) << 16;
  return x.f;
}
__device__ __forceinline__ unsigned short f2b(float f) {
  union { float f; unsigned int i; } x;
  x.f = f;
  unsigned int i = x.i;
  i += 0x7fffu + ((i >> 16) & 1u);  // RNE
  return (unsigned short)(i >> 16);
}

__device__ __forceinline__ void async_copy16(const void* g, void* l) {
  __builtin_amdgcn_global_load_lds(
      (const __attribute__((address_space(1))) unsigned int*)g,
      (__attribute__((address_space(3))) unsigned int*)l, 16, 0, 0);
}

// --- storage-format detector: fp32 storage => even ushorts are mantissa bits
__global__ void detect_fmt(const unsigned short* __restrict__ x, int* flag) {
  __shared__ int cnt;
  if (threadIdx.x == 0) cnt = 0;
  __syncthreads();
  int c = 0;
  for (int i = threadIdx.x * 2; i < 8192; i += 512) {
    unsigned e = (x[i] >> 7) & 0xFF;
    if (e >= 0x90) ++c;
  }
  atomicAdd(&cnt, c);
  __syncthreads();
  if (threadIdx.x == 0) *flag = (cnt > 64) ? 1 : 0;
}

// --- one fused conversion of all 10 inputs into a contiguous bf16 concat
struct CvtArgs { const void* src[10]; };

__global__ __launch_bounds__(256) void convert_all(
    CvtArgs a, unsigned short* __restrict__ dst, const int* __restrict__ flag) {
  const bool f32 = (*flag != 0);
  const long nchunk = 2621952;  // 20975616 / 8
  for (long c = blockIdx.x * 256L + threadIdx.x; c < nchunk;
       c += 1024L * 256) {
    const long flat = c * 8;
    int t; long off;
    if      (flat < 8388608)  { t = 0; off = 0; }
    else if (flat < 16777216) { t = 1; off = 8388608; }
    else if (flat < 17825792) { t = 2; off = 16777216; }
    else if (flat < 17826816) { t = 3; off = 17825792; }
    else if (flat < 18875392) { t = 4; off = 17826816; }
    else if (flat < 18876416) { t = 5; off = 18875392; }
    else if (flat < 19924992) { t = 6; off = 18876416; }
    else if (flat < 19926016) { t = 7; off = 19924992; }
    else if (flat < 20974592) { t = 8; off = 19926016; }
    else                      { t = 9; off = 20974592; }
    const long li = flat - off;
    if (f32) {
      const float* s = (const float*)a.src[t] + li;
      const f32x4 lo = *(const f32x4*)s;
      const f32x4 hi = *(const f32x4*)(s + 4);
      ushort8 o;
      o[0] = f2b(lo[0]); o[1] = f2b(lo[1]); o[2] = f2b(lo[2]); o[3] = f2b(lo[3]);
      o[4] = f2b(hi[0]); o[5] = f2b(hi[1]); o[6] = f2b(hi[2]); o[7] = f2b(hi[3]);
      *(ushort8*)(dst + flat) = o;
    } else {
      *(ushort8*)(dst + flat) =
          *(const ushort8*)((const unsigned short*)a.src[t] + li);
    }
  }
}

#define MODE_BIAS 0  // bf16 out = acc + bias[n]
#define MODE_RES  2  // bf16 out = acc + res[m,n]
#define MODE_SB   3  // bf16 out = acc * scale
#define MODE_OUT  4  // format-aware out = acc + bias[n]  (fp32 or bf16 store)

// XCD-band swizzle: round-robin XCD = linear%8 (assumed); map so blocks with
// the same logical `by` (same A row-tile) land on one XCD, bx sweeping 0..gx.
__device__ __forceinline__ void xcd_swizzle(int gx, int gy, int& bx, int& by) {
  const int L = blockIdx.y * gx + blockIdx.x;
  const int r = L & 7, m = L >> 3;
  bx = m % gx;
  by = r * (gy >> 3) + m / gx;  // requires gy % 8 == 0
}

// Core NT GEMM: C[m,n] = sum_k A[m,k]*B[n,k] (+epilogue), 128x128 tile,
// KU x BK=32 sub-tiles per barrier, 4 waves (2x2) of 64x64, fp32 accum.
template <int MODE, int KU>
__device__ __forceinline__ void gemm_core(
    const unsigned short* __restrict__ A, const unsigned short* __restrict__ B,
    void* __restrict__ C, const unsigned short* __restrict__ bias,
    const unsigned short* __restrict__ Res, const int* __restrict__ flg,
    int N, int K, float scale, int bx, int by) {
  __shared__ __align__(16) unsigned short As[KU * 128 * 32];
  __shared__ __align__(16) unsigned short Bs[KU * 128 * 32];
  const int tid = threadIdx.x;
  const int wave = tid >> 6, lane = tid & 63;
  const int wm = wave >> 1, wn = wave & 1;
  const int quad = lane >> 4, lrow = lane & 15;

  const long arow0 = (long)by * 128 + (tid >> 2);
  const long brow0 = (long)bx * 128 + (tid >> 2);
  const int cstg = (tid & 3) * 8;
  const unsigned short* ag0 = A + arow0 * K + cstg;
  const unsigned short* ag1 = ag0 + 64L * K;
  const unsigned short* bg0 = B + brow0 * K + cstg;
  const unsigned short* bg1 = bg0 + 64L * K;
  char* lA0 = (char*)As + tid * 16;
  char* lA1 = (char*)As + (256 + tid) * 16;
  char* lB0 = (char*)Bs + tid * 16;
  char* lB1 = (char*)Bs + (256 + tid) * 16;

  f32x4 acc[4][4];
#pragma unroll
  for (int i = 0; i < 4; ++i)
#pragma unroll
    for (int j = 0; j < 4; ++j) acc[i][j] = (f32x4){0.f, 0.f, 0.f, 0.f};

  for (int kt = 0; kt < K; kt += 32 * KU) {
#pragma unroll
    for (int u = 0; u < KU; ++u) {
      async_copy16(ag0 + kt + u * 32, lA0 + u * 8192);
      async_copy16(ag1 + kt + u * 32, lA1 + u * 8192);
      async_copy16(bg0 + kt + u * 32, lB0 + u * 8192);
      async_copy16(bg1 + kt + u * 32, lB1 + u * 8192);
    }
    __syncthreads();
#pragma unroll
    for (int u = 0; u < KU; ++u) {
      const unsigned short* Au = As + u * 4096;
      const unsigned short* Bu = Bs + u * 4096;
      short8 af[4], bfr[4];
#pragma unroll
      for (int i = 0; i < 4; ++i)
        af[i] = *(const short8*)(Au + (wm * 64 + i * 16 + lrow) * 32 + quad * 8);
#pragma unroll
      for (int j = 0; j < 4; ++j)
        bfr[j] =
            *(const short8*)(Bu + (wn * 64 + j * 16 + lrow) * 32 + quad * 8);
#pragma unroll
      for (int i = 0; i < 4; ++i)
#pragma unroll
        for (int j = 0; j < 4; ++j)
          acc[i][j] = __builtin_amdgcn_mfma_f32_16x16x32_bf16(
              af[i], bfr[j], acc[i][j], 0, 0, 0);
    }
    __syncthreads();
  }

  const bool f32out = (MODE == MODE_OUT) ? (*flg != 0) : false;
  // C/D layout: col=lane&15, row=(lane>>4)*4+reg (m89-verified)
#pragma unroll
  for (int i = 0; i < 4; ++i) {
    const long row = (long)by * 128 + wm * 64 + i * 16 + quad * 4;
#pragma unroll
    for (int j = 0; j < 4; ++j) {
      const long col = (long)bx * 128 + wn * 64 + j * 16 + lrow;
#pragma unroll
      for (int r = 0; r < 4; ++r) {
        const float v = acc[i][j][r];
        const long idx = (row + r) * N + col;
        if (MODE == MODE_BIAS) {
          ((unsigned short*)C)[idx] = f2b(v + b2f(bias[col]));
        } else if (MODE == MODE_SB) {
          ((unsigned short*)C)[idx] = f2b(v * scale);
        } else if (MODE == MODE_RES) {
          ((unsigned short*)C)[idx] = f2b(v + b2f(Res[idx]));
        } else {  // MODE_OUT
          const float o = v + b2f(bias[col]);
          if (f32out) ((float*)C)[idx] = o;
          else        ((unsigned short*)C)[idx] = f2b(o);
        }
      }
    }
  }
}

template <int MODE, int KU>
__global__ __launch_bounds__(256, 2) void gemm_nt(
    const unsigned short* __restrict__ A, const unsigned short* __restrict__ B,
    void* __restrict__ C, const unsigned short* __restrict__ bias,
    const unsigned short* __restrict__ Res, const int* __restrict__ flg,
    int N, int K, float scale, long sA, long sB, long sC, long sR) {
  const int bz = blockIdx.z;
  int bx, by;
  xcd_swizzle(gridDim.x, gridDim.y, bx, by);
  const unsigned short* Rb = (MODE == MODE_RES) ? Res + bz * sR : nullptr;
  void* Cb = (MODE == MODE_OUT) ? (void*)((char*)C)
                                : (void*)((unsigned short*)C + bz * sC);
  gemm_core<MODE, KU>(A + bz * sA, B + bz * sB, Cb, bias, Rb, flg, N, K, scale,
                      bx, by);
}

// merged Q/K/V projections: blockIdx.z selects (A,B,C,bias) triple
struct QkvArgs {
  const unsigned short* A[3];
  const unsigned short* B[3];
  unsigned short* C[3];
  const unsigned short* bias[3];
};
__global__ __launch_bounds__(256, 2) void gemm_qkv(QkvArgs a, int N, int K) {
  const int z = blockIdx.z;
  int bx, by;
  xcd_swizzle(gridDim.x, gridDim.y, bx, by);
  gemm_core<MODE_BIAS, 2>(a.A[z], a.B[z], a.C[z], a.bias[z], nullptr, nullptr,
                          N, K, 1.f, bx, by);
}

// out[b][c][r] = in[b][r][c]; grid (cols/32, rows/32, batch)
__global__ __launch_bounds__(256) void transpose2d(
    const unsigned short* __restrict__ in, unsigned short* __restrict__ out,
    int rows, int cols) {
  __shared__ unsigned short tile[32][33];
  const long b = blockIdx.z;
  in += b * (long)rows * cols;
  out += b * (long)rows * cols;
  const int r0 = blockIdx.y * 32, c0 = blockIdx.x * 32;
  const int tx = threadIdx.x & 31, ty = threadIdx.x >> 5;
#pragma unroll
  for (int i = 0; i < 32; i += 8)
    tile[ty + i][tx] = in[(long)(r0 + ty + i) * cols + (c0 + tx)];
  __syncthreads();
#pragma unroll
  for (int i = 0; i < 32; i += 8)
    out[(long)(c0 + ty + i) * rows + (r0 + tx)] = tile[tx][ty + i];
}

// in-place row softmax over 2048 bf16 scores; one block per row
__global__ __launch_bounds__(256) void softmax_rows(
    unsigned short* __restrict__ SP) {
  unsigned short* s = SP + blockIdx.x * 2048L;
  const int tid = threadIdx.x;
  float v[8];
#pragma unroll
  for (int i = 0; i < 8; ++i) v[i] = b2f(s[tid + 256 * i]);
  float m = v[0];
#pragma unroll
  for (int i = 1; i < 8; ++i) m = fmaxf(m, v[i]);
#pragma unroll
  for (int off = 32; off > 0; off >>= 1) m = fmaxf(m, __shfl_xor(m, off));
  __shared__ float redm[4], reds[4];
  if ((tid & 63) == 0) redm[tid >> 6] = m;
  __syncthreads();
  m = fmaxf(fmaxf(redm[0], redm[1]), fmaxf(redm[2], redm[3]));
  float sum = 0.f;
#pragma unroll
  for (int i = 0; i < 8; ++i) {
    v[i] = __expf(v[i] - m);
    sum += v[i];
  }
#pragma unroll
  for (int off = 32; off > 0; off >>= 1) sum += __shfl_xor(sum, off);
  if ((tid & 63) == 0) reds[tid >> 6] = sum;
  __syncthreads();
  sum = reds[0] + reds[1] + reds[2] + reds[3];
  const float inv = 1.0f / sum;
#pragma unroll
  for (int i = 0; i < 8; ++i) s[tid + 256 * i] = f2b(v[i] * inv);
}

extern "C" void kernel_launch(void* const* d_in, const int* in_sizes, int n_in,
                              void* d_out, int out_size, void* d_ws,
                              size_t ws_size, hipStream_t stream) {
  char* ws = (char*)d_ws;
  const long MB = 1 << 20;
  unsigned short* C0  = (unsigned short*)ws;  // bf16 concat of inputs
  unsigned short* xb  = C0;
  unsigned short* ceb = C0 + 8388608;
  unsigned short* Wqb = C0 + 16777216;
  unsigned short* bqb = C0 + 17825792;
  unsigned short* Wkb = C0 + 17826816;
  unsigned short* bkb = C0 + 18875392;
  unsigned short* Wvb = C0 + 18876416;
  unsigned short* bvb = C0 + 19924992;
  unsigned short* Wob = C0 + 19926016;
  unsigned short* bob = C0 + 20974592;
  int*            flg = (int*)(ws + 41 * MB);
  unsigned short* Q   = (unsigned short*)(ws + 42 * MB);  // 42-58
  unsigned short* Kp  = (unsigned short*)(ws + 58 * MB);  // 58-74
  unsigned short* Vp  = (unsigned short*)(ws + 74 * MB);  // 74-90
  unsigned short* S   = (unsigned short*)(ws + 90 * MB);  // 90-122 (->P)
  unsigned short* Vt  = Q;   // reuse Q slot after QK^T
  unsigned short* Ar  = Kp;  // reuse K slot after QK^T

  const dim3 blk(256);
  const float scale = 0.03125f;  // 1/sqrt(1024)

  detect_fmt<<<dim3(1), dim3(256), 0, stream>>>((const unsigned short*)d_in[0],
                                                flg);
  CvtArgs ca;
  for (int i = 0; i < 10; ++i) ca.src[i] = d_in[i];
  convert_all<<<dim3(1024), blk, 0, stream>>>(ca, C0, flg);

  // merged QKV projections: M=8192 (batch folded), N=K=1024, 1536 blocks
  QkvArgs qa;
  qa.A[0] = xb;  qa.A[1] = ceb; qa.A[2] = ceb;
  qa.B[0] = Wqb; qa.B[1] = Wkb; qa.B[2] = Wvb;
  qa.C[0] = Q;   qa.C[1] = Kp;  qa.C[2] = Vp;
  qa.bias[0] = bqb; qa.bias[1] = bkb; qa.bias[2] = bvb;
  gemm_qkv<<<dim3(8, 64, 3), blk, 0, stream>>>(qa, 1024, 1024);

  // S = QK^T * scale (bf16), per batch 2048x2048, K=1024
  gemm_nt<MODE_SB, 2><<<dim3(16, 16, 4), blk, 0, stream>>>(
      Q, Kp, S, nullptr, nullptr, nullptr, 2048, 1024, scale,
      2048L * 1024, 2048L * 1024, 2048L * 2048, 0);

  // Vt = V^T per batch (into dead Q slot)
  transpose2d<<<dim3(32, 64, 4), blk, 0, stream>>>(Vp, Vt, 2048, 1024);

  // P = softmax(S) in place
  softmax_rows<<<dim3(8192), blk, 0, stream>>>(S);

  // A = x + P@V : per batch M=2048, N=1024, K=2048 (B=Vt, NT)
  gemm_nt<MODE_RES, 2><<<dim3(8, 16, 4), blk, 0, stream>>>(
      S, Vt, Ar, nullptr, xb, nullptr, 1024, 2048, 1.f,
      2048L * 2048, 1024L * 2048, 2048L * 1024, 2048L * 1024);

  // out = A@Wo^T + bo, written straight to d_out in detected format
  gemm_nt<MODE_OUT, 2><<<dim3(8, 64, 1), blk, 0, stream>>>(
      Ar, Wob, d_out, bob, nullptr, flg, 1024, 1024, 1.f, 0, 0, 0, 0);
}

// Round 5
// 327.168 us; speedup vs baseline: 1.4154x; 1.0134x over previous
//
#include <hip/hip_runtime.h>

// ---------------------------------------------------------------------------
// SpatialTransformer attention, dtype-robust (fp32 vs bf16 storage detect).
// Round 5: V^T fused into QKV epilogue (transposed ushort4 stores, transpose
// kernel dropped); softmax vectorized to ushort8. GEMM core unchanged from
// round 4 (128x128 tile, KU=2, XCD-band swizzle, global_load_lds width=16,
// mfma_f32_16x16x32_bf16) — it sits at the m97 ~830 TF plateau.
// ---------------------------------------------------------------------------

typedef __attribute__((ext_vector_type(8))) short short8;
typedef __attribute__((ext_vector_type(8))) unsigned short ushort8;
typedef __attribute__((ext_vector_type(4))) unsigned short ushort4v;
typedef __attribute__((ext_vector_type(4))) float f32x4;

__device__ __forceinline__ float b2f(unsigned short u) {
  union { unsigned int i; float f; } x;
  x.i = ((unsigned int)u) << 16;
  return x.f;
}
__device__ __forceinline__ unsigned short f2b(float f) {
  union { float f; unsigned int i; } x;
  x.f = f;
  unsigned int i = x.i;
  i += 0x7fffu + ((i >> 16) & 1u);  // RNE
  return (unsigned short)(i >> 16);
}

__device__ __forceinline__ void async_copy16(const void* g, void* l) {
  __builtin_amdgcn_global_load_lds(
      (const __attribute__((address_space(1))) unsigned int*)g,
      (__attribute__((address_space(3))) unsigned int*)l, 16, 0, 0);
}

// --- storage-format detector: fp32 storage => even ushorts are mantissa bits
__global__ void detect_fmt(const unsigned short* __restrict__ x, int* flag) {
  __shared__ int cnt;
  if (threadIdx.x == 0) cnt = 0;
  __syncthreads();
  int c = 0;
  for (int i = threadIdx.x * 2; i < 8192; i += 512) {
    unsigned e = (x[i] >> 7) & 0xFF;
    if (e >= 0x90) ++c;
  }
  atomicAdd(&cnt, c);
  __syncthreads();
  if (threadIdx.x == 0) *flag = (cnt > 64) ? 1 : 0;
}

// --- one fused conversion of all 10 inputs into a contiguous bf16 concat
struct CvtArgs { const void* src[10]; };

__global__ __launch_bounds__(256) void convert_all(
    CvtArgs a, unsigned short* __restrict__ dst, const int* __restrict__ flag) {
  const bool f32 = (*flag != 0);
  const long nchunk = 2621952;  // 20975616 / 8
  for (long c = blockIdx.x * 256L + threadIdx.x; c < nchunk;
       c += 1024L * 256) {
    const long flat = c * 8;
    int t; long off;
    if      (flat < 8388608)  { t = 0; off = 0; }
    else if (flat < 16777216) { t = 1; off = 8388608; }
    else if (flat < 17825792) { t = 2; off = 16777216; }
    else if (flat < 17826816) { t = 3; off = 17825792; }
    else if (flat < 18875392) { t = 4; off = 17826816; }
    else if (flat < 18876416) { t = 5; off = 18875392; }
    else if (flat < 19924992) { t = 6; off = 18876416; }
    else if (flat < 19926016) { t = 7; off = 19924992; }
    else if (flat < 20974592) { t = 8; off = 19926016; }
    else                      { t = 9; off = 20974592; }
    const long li = flat - off;
    if (f32) {
      const float* s = (const float*)a.src[t] + li;
      const f32x4 lo = *(const f32x4*)s;
      const f32x4 hi = *(const f32x4*)(s + 4);
      ushort8 o;
      o[0] = f2b(lo[0]); o[1] = f2b(lo[1]); o[2] = f2b(lo[2]); o[3] = f2b(lo[3]);
      o[4] = f2b(hi[0]); o[5] = f2b(hi[1]); o[6] = f2b(hi[2]); o[7] = f2b(hi[3]);
      *(ushort8*)(dst + flat) = o;
    } else {
      *(ushort8*)(dst + flat) =
          *(const ushort8*)((const unsigned short*)a.src[t] + li);
    }
  }
}

#define MODE_BIAS 0  // bf16 out = acc + bias[n]  (vt: transposed V^T store)
#define MODE_RES  2  // bf16 out = acc + res[m,n]
#define MODE_SB   3  // bf16 out = acc * scale
#define MODE_OUT  4  // format-aware out = acc + bias[n]  (fp32 or bf16 store)

// XCD-band swizzle: round-robin XCD = linear%8 (assumed); blocks sharing a
// logical `by` (same A row-tile) land on one XCD, bx sweeping 0..gx.
__device__ __forceinline__ void xcd_swizzle(int gx, int gy, int& bx, int& by) {
  const int L = blockIdx.y * gx + blockIdx.x;
  const int r = L & 7, m = L >> 3;
  bx = m % gx;
  by = r * (gy >> 3) + m / gx;  // requires gy % 8 == 0
}

// Core NT GEMM: C[m,n] = sum_k A[m,k]*B[n,k] (+epilogue), 128x128 tile,
// KU x BK=32 sub-tiles per barrier, 4 waves (2x2) of 64x64, fp32 accum.
// vt (MODE_BIAS only): store transposed to C2 as [n][m-within-batch].
template <int MODE, int KU>
__device__ __forceinline__ void gemm_core(
    const unsigned short* __restrict__ A, const unsigned short* __restrict__ B,
    void* __restrict__ C, const unsigned short* __restrict__ bias,
    const unsigned short* __restrict__ Res, const int* __restrict__ flg,
    int N, int K, float scale, int bx, int by, int vt) {
  __shared__ __align__(16) unsigned short As[KU * 128 * 32];
  __shared__ __align__(16) unsigned short Bs[KU * 128 * 32];
  const int tid = threadIdx.x;
  const int wave = tid >> 6, lane = tid & 63;
  const int wm = wave >> 1, wn = wave & 1;
  const int quad = lane >> 4, lrow = lane & 15;

  const long arow0 = (long)by * 128 + (tid >> 2);
  const long brow0 = (long)bx * 128 + (tid >> 2);
  const int cstg = (tid & 3) * 8;
  const unsigned short* ag0 = A + arow0 * K + cstg;
  const unsigned short* ag1 = ag0 + 64L * K;
  const unsigned short* bg0 = B + brow0 * K + cstg;
  const unsigned short* bg1 = bg0 + 64L * K;
  char* lA0 = (char*)As + tid * 16;
  char* lA1 = (char*)As + (256 + tid) * 16;
  char* lB0 = (char*)Bs + tid * 16;
  char* lB1 = (char*)Bs + (256 + tid) * 16;

  f32x4 acc[4][4];
#pragma unroll
  for (int i = 0; i < 4; ++i)
#pragma unroll
    for (int j = 0; j < 4; ++j) acc[i][j] = (f32x4){0.f, 0.f, 0.f, 0.f};

  for (int kt = 0; kt < K; kt += 32 * KU) {
#pragma unroll
    for (int u = 0; u < KU; ++u) {
      async_copy16(ag0 + kt + u * 32, lA0 + u * 8192);
      async_copy16(ag1 + kt + u * 32, lA1 + u * 8192);
      async_copy16(bg0 + kt + u * 32, lB0 + u * 8192);
      async_copy16(bg1 + kt + u * 32, lB1 + u * 8192);
    }
    __syncthreads();
#pragma unroll
    for (int u = 0; u < KU; ++u) {
      const unsigned short* Au = As + u * 4096;
      const unsigned short* Bu = Bs + u * 4096;
      short8 af[4], bfr[4];
#pragma unroll
      for (int i = 0; i < 4; ++i)
        af[i] = *(const short8*)(Au + (wm * 64 + i * 16 + lrow) * 32 + quad * 8);
#pragma unroll
      for (int j = 0; j < 4; ++j)
        bfr[j] =
            *(const short8*)(Bu + (wn * 64 + j * 16 + lrow) * 32 + quad * 8);
#pragma unroll
      for (int i = 0; i < 4; ++i)
#pragma unroll
        for (int j = 0; j < 4; ++j)
          acc[i][j] = __builtin_amdgcn_mfma_f32_16x16x32_bf16(
              af[i], bfr[j], acc[i][j], 0, 0, 0);
    }
    __syncthreads();
  }

  const bool f32out = (MODE == MODE_OUT) ? (*flg != 0) : false;
  // C/D layout: col=lane&15, row=(lane>>4)*4+reg (m89-verified)
#pragma unroll
  for (int i = 0; i < 4; ++i) {
    const long row = (long)by * 128 + wm * 64 + i * 16 + quad * 4;
#pragma unroll
    for (int j = 0; j < 4; ++j) {
      const long col = (long)bx * 128 + wn * 64 + j * 16 + lrow;
      if (MODE == MODE_BIAS && vt) {
        // V^T store: Vt[b][col][kv], 4 consecutive rows -> one 8B store
        const float bb = b2f(bias[col]);
        ushort4v pk;
#pragma unroll
        for (int r = 0; r < 4; ++r) pk[r] = f2b(acc[i][j][r] + bb);
        const long b = row >> 11, kvr = row & 2047;
        *(ushort4v*)((unsigned short*)C + b * 2097152 + col * 2048 + kvr) = pk;
        continue;
      }
#pragma unroll
      for (int r = 0; r < 4; ++r) {
        const float v = acc[i][j][r];
        const long idx = (row + r) * N + col;
        if (MODE == MODE_BIAS) {
          ((unsigned short*)C)[idx] = f2b(v + b2f(bias[col]));
        } else if (MODE == MODE_SB) {
          ((unsigned short*)C)[idx] = f2b(v * scale);
        } else if (MODE == MODE_RES) {
          ((unsigned short*)C)[idx] = f2b(v + b2f(Res[idx]));
        } else {  // MODE_OUT
          const float o = v + b2f(bias[col]);
          if (f32out) ((float*)C)[idx] = o;
          else        ((unsigned short*)C)[idx] = f2b(o);
        }
      }
    }
  }
}

template <int MODE, int KU>
__global__ __launch_bounds__(256, 2) void gemm_nt(
    const unsigned short* __restrict__ A, const unsigned short* __restrict__ B,
    void* __restrict__ C, const unsigned short* __restrict__ bias,
    const unsigned short* __restrict__ Res, const int* __restrict__ flg,
    int N, int K, float scale, long sA, long sB, long sC, long sR) {
  const int bz = blockIdx.z;
  int bx, by;
  xcd_swizzle(gridDim.x, gridDim.y, bx, by);
  const unsigned short* Rb = (MODE == MODE_RES) ? Res + bz * sR : nullptr;
  void* Cb = (MODE == MODE_OUT) ? (void*)((char*)C)
                                : (void*)((unsigned short*)C + bz * sC);
  gemm_core<MODE, KU>(A + bz * sA, B + bz * sB, Cb, bias, Rb, flg, N, K, scale,
                      bx, by, 0);
}

// merged Q/K/V projections: blockIdx.z selects (A,B,C,bias); z==2 (V) stores
// transposed into the Vt buffer.
struct QkvArgs {
  const unsigned short* A[3];
  const unsigned short* B[3];
  unsigned short* C[3];
  const unsigned short* bias[3];
};
__global__ __launch_bounds__(256, 2) void gemm_qkv(QkvArgs a, int N, int K) {
  const int z = blockIdx.z;
  int bx, by;
  xcd_swizzle(gridDim.x, gridDim.y, bx, by);
  gemm_core<MODE_BIAS, 2>(a.A[z], a.B[z], a.C[z], a.bias[z], nullptr, nullptr,
                          N, K, 1.f, bx, by, z == 2 ? 1 : 0);
}

// in-place row softmax over 2048 bf16 scores; one block per row; 16B/lane
__global__ __launch_bounds__(256) void softmax_rows(
    unsigned short* __restrict__ SP) {
  unsigned short* s = SP + blockIdx.x * 2048L;
  const int tid = threadIdx.x;
  const ushort8 raw = *(const ushort8*)(s + tid * 8);
  float v[8];
#pragma unroll
  for (int i = 0; i < 8; ++i) v[i] = b2f(raw[i]);
  float m = v[0];
#pragma unroll
  for (int i = 1; i < 8; ++i) m = fmaxf(m, v[i]);
#pragma unroll
  for (int off = 32; off > 0; off >>= 1) m = fmaxf(m, __shfl_xor(m, off));
  __shared__ float redm[4], reds[4];
  if ((tid & 63) == 0) redm[tid >> 6] = m;
  __syncthreads();
  m = fmaxf(fmaxf(redm[0], redm[1]), fmaxf(redm[2], redm[3]));
  float sum = 0.f;
#pragma unroll
  for (int i = 0; i < 8; ++i) {
    v[i] = __expf(v[i] - m);
    sum += v[i];
  }
#pragma unroll
  for (int off = 32; off > 0; off >>= 1) sum += __shfl_xor(sum, off);
  if ((tid & 63) == 0) reds[tid >> 6] = sum;
  __syncthreads();
  sum = reds[0] + reds[1] + reds[2] + reds[3];
  const float inv = 1.0f / sum;
  ushort8 o;
#pragma unroll
  for (int i = 0; i < 8; ++i) o[i] = f2b(v[i] * inv);
  *(ushort8*)(s + tid * 8) = o;
}

extern "C" void kernel_launch(void* const* d_in, const int* in_sizes, int n_in,
                              void* d_out, int out_size, void* d_ws,
                              size_t ws_size, hipStream_t stream) {
  char* ws = (char*)d_ws;
  const long MB = 1 << 20;
  unsigned short* C0  = (unsigned short*)ws;  // bf16 concat of inputs
  unsigned short* xb  = C0;
  unsigned short* ceb = C0 + 8388608;
  unsigned short* Wqb = C0 + 16777216;
  unsigned short* bqb = C0 + 17825792;
  unsigned short* Wkb = C0 + 17826816;
  unsigned short* bkb = C0 + 18875392;
  unsigned short* Wvb = C0 + 18876416;
  unsigned short* bvb = C0 + 19924992;
  unsigned short* Wob = C0 + 19926016;
  unsigned short* bob = C0 + 20974592;
  int*            flg = (int*)(ws + 41 * MB);
  unsigned short* Q   = (unsigned short*)(ws + 42 * MB);  // 42-58
  unsigned short* Kp  = (unsigned short*)(ws + 58 * MB);  // 58-74
  unsigned short* Vt  = (unsigned short*)(ws + 74 * MB);  // 74-90 (V^T direct)
  unsigned short* S   = (unsigned short*)(ws + 90 * MB);  // 90-122 (->P)
  unsigned short* Ar  = Kp;  // reuse K slot after QK^T

  const dim3 blk(256);
  const float scale = 0.03125f;  // 1/sqrt(1024)

  detect_fmt<<<dim3(1), dim3(256), 0, stream>>>((const unsigned short*)d_in[0],
                                                flg);
  CvtArgs ca;
  for (int i = 0; i < 10; ++i) ca.src[i] = d_in[i];
  convert_all<<<dim3(1024), blk, 0, stream>>>(ca, C0, flg);

  // merged QKV projections: M=8192 (batch folded), N=K=1024; V goes out
  // transposed into Vt ([b][1024][2048])
  QkvArgs qa;
  qa.A[0] = xb;  qa.A[1] = ceb; qa.A[2] = ceb;
  qa.B[0] = Wqb; qa.B[1] = Wkb; qa.B[2] = Wvb;
  qa.C[0] = Q;   qa.C[1] = Kp;  qa.C[2] = Vt;
  qa.bias[0] = bqb; qa.bias[1] = bkb; qa.bias[2] = bvb;
  gemm_qkv<<<dim3(8, 64, 3), blk, 0, stream>>>(qa, 1024, 1024);

  // S = QK^T * scale (bf16), per batch 2048x2048, K=1024
  gemm_nt<MODE_SB, 2><<<dim3(16, 16, 4), blk, 0, stream>>>(
      Q, Kp, S, nullptr, nullptr, nullptr, 2048, 1024, scale,
      2048L * 1024, 2048L * 1024, 2048L * 2048, 0);

  // P = softmax(S) in place
  softmax_rows<<<dim3(8192), blk, 0, stream>>>(S);

  // A = x + P@V : per batch M=2048, N=1024, K=2048 (B=Vt, NT)
  gemm_nt<MODE_RES, 2><<<dim3(8, 16, 4), blk, 0, stream>>>(
      S, Vt, Ar, nullptr, xb, nullptr, 1024, 2048, 1.f,
      2048L * 2048, 1024L * 2048, 2048L * 1024, 2048L * 1024);

  // out = A@Wo^T + bo, written straight to d_out in detected format
  gemm_nt<MODE_OUT, 2><<<dim3(8, 64, 1), blk, 0, stream>>>(
      Ar, Wob, d_out, bob, nullptr, flg, 1024, 1024, 1.f, 0, 0, 0, 0);
}